// Round 9
// baseline (306.408 us; speedup 1.0000x reference)
//
#include <hip/hip_runtime.h>
#include <hip/hip_bf16.h>

constexpr int NR = 12288;   // nodes
constexpr int KF = 256;     // in features
constexpr int DF = 128;     // out features
constexpr int CH = 8;       // column chunks
constexpr int CW = NR / CH; // 1536 cols per chunk
constexpr int NSTEP = CW / 32;      // 48
constexpr int ROWS = 192;   // Q-rows per flash block (12 waves x 16 rows)
constexpr int BMW = NR / 32;        // bitmask words per row (384)
#define NEGBIG (-1e30f)

typedef __attribute__((ext_vector_type(8))) __bf16 bf16x8;
typedef __attribute__((ext_vector_type(4))) float  f32x4;

__device__ __forceinline__ unsigned short f2bf(float f) {
    union { float f; unsigned u; } v; v.f = f;
    unsigned r = v.u + 0x7FFFu + ((v.u >> 16) & 1u);
    return (unsigned short)(r >> 16);
}

__device__ __forceinline__ void gload16(const void* g, void* l) {
    __builtin_amdgcn_global_load_lds(
        (const __attribute__((address_space(1))) void*)g,
        (__attribute__((address_space(3))) void*)l, 16, 0, 0);
}

// ---------- Kernel A: fused {h=x@W -> hbT,s1,s2} + {adj -> bitmask} ----------
// 512 blocks x 256 thr. Blocks 0..191 do one 64-row GEMM tile first, then a
// ~13% shorter compress slice (skew hides GEMM under the adj stream).
__global__ __launch_bounds__(256) void k_gemm_comp(
    const float* __restrict__ x, const float* __restrict__ W,
    const float* __restrict__ a1, const float* __restrict__ a2,
    const int* __restrict__ adj,
    unsigned short* __restrict__ hbT, float* __restrict__ s1, float* __restrict__ s2,
    unsigned* __restrict__ bm)
{
    __shared__ __align__(16) float xs[64][65];
    __shared__ __align__(16) float ws[64][132];
    const int t   = threadIdx.x;
    const int bid = blockIdx.x;

    if (bid < NR / 64) {
        const int tx = t & 15, ty = t >> 4;
        const int rowbase = bid * 64;

        float acc[4][8];
#pragma unroll
        for (int i = 0; i < 4; ++i)
#pragma unroll
            for (int j = 0; j < 8; ++j) acc[i][j] = 0.f;

        for (int kt = 0; kt < KF; kt += 64) {
            {   // stage x tile [64][64]
                int row = t >> 2, k0 = (t & 3) * 16;
                const float4* src = (const float4*)(x + (size_t)(rowbase + row) * KF + kt + k0);
                float4 v0 = src[0], v1 = src[1], v2 = src[2], v3 = src[3];
                xs[row][k0+ 0]=v0.x; xs[row][k0+ 1]=v0.y; xs[row][k0+ 2]=v0.z; xs[row][k0+ 3]=v0.w;
                xs[row][k0+ 4]=v1.x; xs[row][k0+ 5]=v1.y; xs[row][k0+ 6]=v1.z; xs[row][k0+ 7]=v1.w;
                xs[row][k0+ 8]=v2.x; xs[row][k0+ 9]=v2.y; xs[row][k0+10]=v2.z; xs[row][k0+11]=v2.w;
                xs[row][k0+12]=v3.x; xs[row][k0+13]=v3.y; xs[row][k0+14]=v3.z; xs[row][k0+15]=v3.w;
            }
            {   // stage W tile [64][128]
                int k = t >> 2, c0 = (t & 3) * 32;
                const float4* src = (const float4*)(W + (size_t)(kt + k) * DF + c0);
#pragma unroll
                for (int j = 0; j < 8; ++j)
                    *(float4*)&ws[k][c0 + j * 4] = src[j];
            }
            __syncthreads();
#pragma unroll 4
            for (int k = 0; k < 64; ++k) {
                float xv[4];
#pragma unroll
                for (int ri = 0; ri < 4; ++ri) xv[ri] = xs[ty * 4 + ri][k];
                float4 w0 = *(float4*)&ws[k][tx * 8];
                float4 w1 = *(float4*)&ws[k][tx * 8 + 4];
#pragma unroll
                for (int ri = 0; ri < 4; ++ri) {
                    acc[ri][0] += xv[ri] * w0.x; acc[ri][1] += xv[ri] * w0.y;
                    acc[ri][2] += xv[ri] * w0.z; acc[ri][3] += xv[ri] * w0.w;
                    acc[ri][4] += xv[ri] * w1.x; acc[ri][5] += xv[ri] * w1.y;
                    acc[ri][6] += xv[ri] * w1.z; acc[ri][7] += xv[ri] * w1.w;
                }
            }
            __syncthreads();
        }
#pragma unroll
        for (int ci = 0; ci < 8; ++ci) {
            int col = tx * 8 + ci;
            ushort4 u;
            u.x = f2bf(acc[0][ci]); u.y = f2bf(acc[1][ci]);
            u.z = f2bf(acc[2][ci]); u.w = f2bf(acc[3][ci]);
            *(ushort4*)(hbT + (size_t)col * NR + rowbase + ty * 4) = u;
        }
        float4 a1lo = *(const float4*)(a1 + tx * 8), a1hi = *(const float4*)(a1 + tx * 8 + 4);
        float4 a2lo = *(const float4*)(a2 + tx * 8), a2hi = *(const float4*)(a2 + tx * 8 + 4);
#pragma unroll
        for (int ri = 0; ri < 4; ++ri) {
            float p1 = acc[ri][0]*a1lo.x + acc[ri][1]*a1lo.y + acc[ri][2]*a1lo.z + acc[ri][3]*a1lo.w
                     + acc[ri][4]*a1hi.x + acc[ri][5]*a1hi.y + acc[ri][6]*a1hi.z + acc[ri][7]*a1hi.w;
            float p2 = acc[ri][0]*a2lo.x + acc[ri][1]*a2lo.y + acc[ri][2]*a2lo.z + acc[ri][3]*a2lo.w
                     + acc[ri][4]*a2hi.x + acc[ri][5]*a2hi.y + acc[ri][6]*a2hi.z + acc[ri][7]*a2hi.w;
#pragma unroll
            for (int off = 8; off > 0; off >>= 1) {
                p1 += __shfl_xor(p1, off);
                p2 += __shfl_xor(p2, off);
            }
            if (tx == 0) {
                s1[rowbase + ty * 4 + ri] = p1;
                s2[rowbase + ty * 4 + ri] = p2;
            }
        }
    }

    // ---- compress slice (all 512 blocks). Slices are multiples of 8 uint4 so
    // every 8-lane pack group is fully intra-slice.
    constexpr size_t T4  = (size_t)NR * NR / 4;  // 37,748,736
    constexpr size_t NGB = 192;
    constexpr size_t G4  = 67584;                // gemm-block share (mult of 256)
    constexpr size_t N4  = 77416;                // other-block share (mult of 8)
    size_t start, end;
    if (bid < (int)NGB) { start = (size_t)bid * G4; end = start + G4; }
    else { start = NGB * G4 + (size_t)(bid - NGB) * N4; end = start + N4; if (end > T4) end = T4; }

    const int lane = t & 63;
    const unsigned sh = (lane & 7) * 4;
    const int4* a4 = (const int4*)adj;
    for (size_t i = start + t; i < end; i += 256) {
        int4 a = a4[i];
        unsigned nib = (unsigned)(a.x > 0) | ((unsigned)(a.y > 0) << 1)
                     | ((unsigned)(a.z > 0) << 2) | ((unsigned)(a.w > 0) << 3);
        unsigned v = nib << sh;
        v |= __shfl_xor(v, 1);
        v |= __shfl_xor(v, 2);
        v |= __shfl_xor(v, 4);
        if ((lane & 7) == 0) bm[i >> 3] = v;
    }
}

// ---------- Kernel A2: global max of s1 (one block) --------------------------
__global__ __launch_bounds__(1024) void k_gmax(
    const float* __restrict__ s1, float* __restrict__ gmax)
{
    __shared__ float red[16];
    const int t = threadIdx.x;
    float m = NEGBIG;
    const float4* s4 = (const float4*)s1;
    for (int i = t; i < NR / 4; i += 1024) {
        float4 v = s4[i];
        m = fmaxf(fmaxf(v.x, v.y), fmaxf(fmaxf(v.z, v.w), m));
    }
#pragma unroll
    for (int off = 32; off > 0; off >>= 1) m = fmaxf(m, __shfl_xor(m, off));
    if ((t & 63) == 0) red[t >> 6] = m;
    __syncthreads();
    if (t < 16) {
        m = red[t];
#pragma unroll
        for (int off = 8; off > 0; off >>= 1) m = fmaxf(m, __shfl_xor(m, off));
        if (t == 0) gmax[0] = m;
    }
}

// ---------- Kernel B: flash from BITMASK. 192 rows/block (12 waves x 16 rows),
// grid 64x8 = 512 blocks = exactly 2/CU (24 waves/CU). Per-iter VMEM = 1
// gload16 for waves 0-7 only (hbT, L2-resident). Ring-3, counted vmcnt(1).
__global__ __launch_bounds__(768, 6) void k_flash(
    const unsigned* __restrict__ bm, const unsigned short* __restrict__ hbT,
    const float* __restrict__ s1, const float* __restrict__ s2,
    const float* __restrict__ gmaxp,
    float* __restrict__ num, float* __restrict__ lC)
{
    __shared__ __align__(16) unsigned short hbtring[3][4096]; // 8KB/slot
    __shared__ __align__(16) unsigned       bmlds[ROWS][52];  // 48 + pad (2-way max)
    __shared__ __align__(16) float          s1lds[CW];

    const int t    = threadIdx.x;
    const int wid  = t >> 6, lane = t & 63;
    const int r    = lane & 15, g = lane >> 4;
    const int rowb = blockIdx.x * ROWS;
    const int prow = rowb + wid * 16 + r;
    const int chunk = blockIdx.y;
    const int j0 = chunk * CW;

    // one-time: stage s1 chunk + bitmask tile [192 rows][48 words]
    if (t < CW / 4) *(float4*)&s1lds[t * 4] = *(const float4*)(s1 + j0 + t * 4);
#pragma unroll
    for (int i = 0; i < 3; ++i) {
        int idx = i * 768 + t;               // 2304 uint4 = 192 rows x 12
        int brow = idx / 12, bk = idx % 12;
        uint4 w = *(const uint4*)(bm + (size_t)(rowb + brow) * BMW + chunk * NSTEP + bk * 4);
        *(uint4*)&bmlds[brow][bk * 4] = w;   // 52%4==0 -> 16B aligned
    }

    const float gm  = gmaxp[0];
    const float s2r = s2[prow];
    const float zub = s2r + gm;
    const float Mi  = fmaxf(zub, 0.2f * zub);   // lrelu(upper bound) >= every row logit

    // ---- hbT staging: waves 0-7 stage feats wid*16..+16 via 1 gload16
    const int hrow  = wid * 16 + (lane >> 2);    // valid for wid<8 (guarded issue)
    const int hcol8 = ((lane & 3) ^ ((lane >> 3) & 3)) * 8;
    const unsigned short* hgp0 = hbT + (size_t)hrow * NR + j0 + hcol8;
    const int hldso0 = wid * 16 * 64;
    const int h_base = r * 64 + ((g ^ ((r >> 1) & 3)) * 16);    // + f*1024

#define ISSUE(st) do { \
        const int sl_ = (st) % 3; \
        const size_t go_ = (size_t)(((st) % NSTEP) * 32); \
        if (wid < 8) gload16(hgp0 + go_, (char*)&hbtring[sl_][0] + hldso0); \
    } while (0)

    float lsum = 0.f;
    f32x4 acc[8];
#pragma unroll
    for (int f = 0; f < 8; ++f) acc[f] = f32x4{0.f, 0.f, 0.f, 0.f};

    ISSUE(0);
    ISSUE(1);

    const unsigned* bmrow = &bmlds[wid * 16 + r][0];
    const unsigned gsh = g * 8;

    for (int j = 0; j < NSTEP; ++j) {
        // stage j landed when <=1 of this wave's vmem remain (stage j+1 only).
        if (wid < 8) asm volatile("s_waitcnt vmcnt(1) lgkmcnt(0)" ::: "memory");
        else         asm volatile("s_waitcnt lgkmcnt(0)" ::: "memory");
        __builtin_amdgcn_s_barrier();
        __builtin_amdgcn_sched_barrier(0);
        ISSUE(j + 2);   // slot (j+2)%3 == (j-1)%3, consumed before the barrier

        const unsigned mw = bmrow[j] >> gsh;    // bits 0..7 = this lane's 8 cols
        const float4 Sa = *(const float4*)&s1lds[j * 32 + g * 8];
        const float4 Sb = *(const float4*)&s1lds[j * 32 + g * 8 + 4];

        bf16x8 pf;
#define PROC(bi, ss, idx) { \
            float t0 = (ss) + s2r; \
            float lr = fmaxf(t0, 0.2f * t0); \
            float q  = __expf(lr - Mi); \
            float p  = ((mw >> (bi)) & 1u) ? q : 0.f; \
            lsum += p; \
            pf[idx] = (__bf16)p; }
        PROC(0, Sa.x, 0) PROC(1, Sa.y, 1)
        PROC(2, Sa.z, 2) PROC(3, Sa.w, 3)
        PROC(4, Sb.x, 4) PROC(5, Sb.y, 5)
        PROC(6, Sb.z, 6) PROC(7, Sb.w, 7)
#undef PROC

        const int sl = j % 3;
        const char* hb = (const char*)&hbtring[sl][0] + h_base;
#pragma unroll
        for (int f = 0; f < 8; ++f) {
            bf16x8 bfr = *(const bf16x8*)(hb + f * 1024);
            acc[f] = __builtin_amdgcn_mfma_f32_16x16x32_bf16(pf, bfr, acc[f], 0, 0, 0);
        }
    }
#undef ISSUE

    lsum += __shfl_xor(lsum, 16);
    lsum += __shfl_xor(lsum, 32);
    if (g == 0) lC[(size_t)chunk * NR + prow] = lsum;

    float* nb = num + (size_t)chunk * NR * DF;
#pragma unroll
    for (int f = 0; f < 8; ++f)
#pragma unroll
        for (int q = 0; q < 4; ++q) {
            int row = rowb + wid * 16 + g * 4 + q;   // C/D layout: row=(lane>>4)*4+reg
            nb[(size_t)row * DF + f * 16 + r] = acc[f][q];
        }
}

// ---------- Kernel C: combine chunk partials (shared M_i -> plain sums) ------
__global__ __launch_bounds__(256) void k_comb(
    const float* __restrict__ num, const float* __restrict__ lC,
    float* __restrict__ out)
{
    const int t   = threadIdx.x;
    const int row = blockIdx.x * 2 + (t >> 7);
    const int f   = t & 127;
    float L = 0.f, o = 0.f;
    for (int c = 0; c < CH; ++c) {
        L += lC[(size_t)c * NR + row];
        o += num[(size_t)c * NR * DF + (size_t)row * DF + f];
    }
    out[(size_t)row * DF + f] = o / L;
}

extern "C" void kernel_launch(void* const* d_in, const int* in_sizes, int n_in,
                              void* d_out, int out_size, void* d_ws, size_t ws_size,
                              hipStream_t stream)
{
    const float* x   = (const float*)d_in[0];
    const int*   adj = (const int*)d_in[1];
    const float* W   = (const float*)d_in[2];
    const float* a1  = (const float*)d_in[3];
    const float* a2  = (const float*)d_in[4];
    float* out = (float*)d_out;

    char* p = (char*)d_ws;
    unsigned short* hbT = (unsigned short*)p; p += (size_t)DF * NR * 2;
    unsigned*       bmw = (unsigned*)p;       p += (size_t)NR * BMW * 4;
    float*          s1  = (float*)p;          p += (size_t)NR * 4;
    float*          s2  = (float*)p;          p += (size_t)NR * 4;
    float*          gmx = (float*)p;          p += 256;
    float*          numb = (float*)p;         p += (size_t)CH * NR * DF * 4;
    float*          lC   = (float*)p;

    k_gemm_comp<<<512, 256, 0, stream>>>(x, W, a1, a2, adj, hbT, s1, s2, bmw);
    k_gmax<<<1, 1024, 0, stream>>>(s1, gmx);
    k_flash<<<dim3(NR / ROWS, CH), 768, 0, stream>>>(bmw, hbT, s1, s2, gmx, numb, lC);
    k_comb<<<NR / 2, 256, 0, stream>>>(numb, lC, out);
}

// Round 10
// 222.662 us; speedup vs baseline: 1.3761x; 1.3761x over previous
//
#include <hip/hip_runtime.h>
#include <hip/hip_bf16.h>
#include <hip/hip_fp16.h>

constexpr int NR = 12288;   // nodes
constexpr int KF = 256;     // in features
constexpr int DF = 128;     // out features
constexpr int CH = 16;      // column chunks
constexpr int CW = NR / CH; // 768 cols per chunk
constexpr int NSTEP = CW / 32;      // 24
constexpr int ROWS = 128;   // Q-rows per flash block (8 waves x 16 rows)
constexpr int BMW = NR / 32;        // bitmask words per row (384)
#define NEGBIG (-1e30f)

typedef __attribute__((ext_vector_type(8))) __bf16 bf16x8;
typedef __attribute__((ext_vector_type(4))) float  f32x4;

__device__ __forceinline__ unsigned short f2bf(float f) {
    union { float f; unsigned u; } v; v.f = f;
    unsigned r = v.u + 0x7FFFu + ((v.u >> 16) & 1u);
    return (unsigned short)(r >> 16);
}

__device__ __forceinline__ void gload16(const void* g, void* l) {
    __builtin_amdgcn_global_load_lds(
        (const __attribute__((address_space(1))) void*)g,
        (__attribute__((address_space(3))) void*)l, 16, 0, 0);
}

// ---------- Kernel 0: adj (int32 0/1) -> bitmask. Pure stream, ~604 MB read.
__global__ __launch_bounds__(256) void k_compress(
    const int* __restrict__ adj, unsigned* __restrict__ bm)
{
    const int lane = threadIdx.x & 63;
    const unsigned sh = (lane & 7) * 4;
    size_t i = (size_t)blockIdx.x * 256 + threadIdx.x;
    const size_t total4 = (size_t)NR * NR / 4;
    const size_t stride = (size_t)gridDim.x * 256;
    const int4* a4 = (const int4*)adj;
    for (; i < total4; i += stride) {
        int4 a = a4[i];
        unsigned nib = (unsigned)(a.x > 0) | ((unsigned)(a.y > 0) << 1)
                     | ((unsigned)(a.z > 0) << 2) | ((unsigned)(a.w > 0) << 3);
        unsigned v = nib << sh;
        v |= __shfl_xor(v, 1);
        v |= __shfl_xor(v, 2);
        v |= __shfl_xor(v, 4);
        if ((lane & 7) == 0) bm[i >> 3] = v;
    }
}

// ---------- Kernel A: h = x@W (fp32 regs), emit hbT (bf16, transposed) + s1/s2
__global__ __launch_bounds__(256) void k_gemm_h(
    const float* __restrict__ x, const float* __restrict__ W,
    const float* __restrict__ a1, const float* __restrict__ a2,
    unsigned short* __restrict__ hbT, float* __restrict__ s1, float* __restrict__ s2)
{
    __shared__ __align__(16) float xs[64][65];
    __shared__ __align__(16) float ws[64][132];
    const int t  = threadIdx.x;
    const int tx = t & 15, ty = t >> 4;
    const int rowbase = blockIdx.x * 64;

    float acc[4][8];
#pragma unroll
    for (int i = 0; i < 4; ++i)
#pragma unroll
        for (int j = 0; j < 8; ++j) acc[i][j] = 0.f;

    for (int kt = 0; kt < KF; kt += 64) {
        {   // stage x tile [64][64]
            int row = t >> 2, k0 = (t & 3) * 16;
            const float4* src = (const float4*)(x + (size_t)(rowbase + row) * KF + kt + k0);
            float4 v0 = src[0], v1 = src[1], v2 = src[2], v3 = src[3];
            xs[row][k0+ 0]=v0.x; xs[row][k0+ 1]=v0.y; xs[row][k0+ 2]=v0.z; xs[row][k0+ 3]=v0.w;
            xs[row][k0+ 4]=v1.x; xs[row][k0+ 5]=v1.y; xs[row][k0+ 6]=v1.z; xs[row][k0+ 7]=v1.w;
            xs[row][k0+ 8]=v2.x; xs[row][k0+ 9]=v2.y; xs[row][k0+10]=v2.z; xs[row][k0+11]=v2.w;
            xs[row][k0+12]=v3.x; xs[row][k0+13]=v3.y; xs[row][k0+14]=v3.z; xs[row][k0+15]=v3.w;
        }
        {   // stage W tile [64][128]
            int k = t >> 2, c0 = (t & 3) * 32;
            const float4* src = (const float4*)(W + (size_t)(kt + k) * DF + c0);
#pragma unroll
            for (int j = 0; j < 8; ++j)
                *(float4*)&ws[k][c0 + j * 4] = src[j];
        }
        __syncthreads();
#pragma unroll 4
        for (int k = 0; k < 64; ++k) {
            float xv[4];
#pragma unroll
            for (int ri = 0; ri < 4; ++ri) xv[ri] = xs[ty * 4 + ri][k];
            float4 w0 = *(float4*)&ws[k][tx * 8];
            float4 w1 = *(float4*)&ws[k][tx * 8 + 4];
#pragma unroll
            for (int ri = 0; ri < 4; ++ri) {
                acc[ri][0] += xv[ri] * w0.x; acc[ri][1] += xv[ri] * w0.y;
                acc[ri][2] += xv[ri] * w0.z; acc[ri][3] += xv[ri] * w0.w;
                acc[ri][4] += xv[ri] * w1.x; acc[ri][5] += xv[ri] * w1.y;
                acc[ri][6] += xv[ri] * w1.z; acc[ri][7] += xv[ri] * w1.w;
            }
        }
        __syncthreads();
    }
#pragma unroll
    for (int ci = 0; ci < 8; ++ci) {
        int col = tx * 8 + ci;
        ushort4 u;
        u.x = f2bf(acc[0][ci]); u.y = f2bf(acc[1][ci]);
        u.z = f2bf(acc[2][ci]); u.w = f2bf(acc[3][ci]);
        *(ushort4*)(hbT + (size_t)col * NR + rowbase + ty * 4) = u;
    }
    float4 a1lo = *(const float4*)(a1 + tx * 8), a1hi = *(const float4*)(a1 + tx * 8 + 4);
    float4 a2lo = *(const float4*)(a2 + tx * 8), a2hi = *(const float4*)(a2 + tx * 8 + 4);
#pragma unroll
    for (int ri = 0; ri < 4; ++ri) {
        float p1 = acc[ri][0]*a1lo.x + acc[ri][1]*a1lo.y + acc[ri][2]*a1lo.z + acc[ri][3]*a1lo.w
                 + acc[ri][4]*a1hi.x + acc[ri][5]*a1hi.y + acc[ri][6]*a1hi.z + acc[ri][7]*a1hi.w;
        float p2 = acc[ri][0]*a2lo.x + acc[ri][1]*a2lo.y + acc[ri][2]*a2lo.z + acc[ri][3]*a2lo.w
                 + acc[ri][4]*a2hi.x + acc[ri][5]*a2hi.y + acc[ri][6]*a2hi.z + acc[ri][7]*a2hi.w;
#pragma unroll
        for (int off = 8; off > 0; off >>= 1) {
            p1 += __shfl_xor(p1, off);
            p2 += __shfl_xor(p2, off);
        }
        if (tx == 0) {
            s1[rowbase + ty * 4 + ri] = p1;
            s2[rowbase + ty * 4 + ri] = p2;
        }
    }
}

// ---------- Kernel A2: global max of s1 (one block) --------------------------
__global__ __launch_bounds__(1024) void k_gmax(
    const float* __restrict__ s1, float* __restrict__ gmax)
{
    __shared__ float red[16];
    const int t = threadIdx.x;
    float m = NEGBIG;
    const float4* s4 = (const float4*)s1;
    for (int i = t; i < NR / 4; i += 1024) {
        float4 v = s4[i];
        m = fmaxf(fmaxf(v.x, v.y), fmaxf(fmaxf(v.z, v.w), m));
    }
#pragma unroll
    for (int off = 32; off > 0; off >>= 1) m = fmaxf(m, __shfl_xor(m, off));
    if ((t & 63) == 0) red[t >> 6] = m;
    __syncthreads();
    if (t < 16) {
        m = red[t];
#pragma unroll
        for (int off = 8; off > 0; off >>= 1) m = fmaxf(m, __shfl_xor(m, off));
        if (t == 0) gmax[0] = m;
    }
}

// ---------- Kernel B: flash from BITMASK. 128 rows/block (8 waves x 16 rows),
// grid 96x16 = 1536 blocks = exactly 3 rounds of 512 slots (2 blocks/CU).
// Per-iter VMEM = 1 gload16/wave (hbT). Ring-3, counted vmcnt(1). fp16 numb out.
__global__ __launch_bounds__(512, 4) void k_flash(
    const unsigned* __restrict__ bm, const unsigned short* __restrict__ hbT,
    const float* __restrict__ s1, const float* __restrict__ s2,
    const float* __restrict__ gmaxp,
    __half* __restrict__ num, float* __restrict__ lC)
{
    __shared__ __align__(16) unsigned short hbtring[3][4096]; // 8KB/slot
    __shared__ __align__(16) unsigned       bmlds[ROWS][28];  // 24 + pad (2-way max, free)
    __shared__ __align__(16) float          s1lds[CW];

    const int t    = threadIdx.x;
    const int wid  = t >> 6, lane = t & 63;
    const int r    = lane & 15, g = lane >> 4;
    const int rowb = blockIdx.x * ROWS;
    const int prow = rowb + wid * 16 + r;
    const int chunk = blockIdx.y;
    const int j0 = chunk * CW;

    // one-time: stage s1 chunk + bitmask tile [128 rows][24 words]
    if (t < CW / 4) *(float4*)&s1lds[t * 4] = *(const float4*)(s1 + j0 + t * 4);
#pragma unroll
    for (int i = 0; i < 2; ++i) {
        int idx = i * 512 + t;               // 768 uint4 = 128 rows x 6
        if (idx < 768) {
            int brow = idx / 6, bk = idx % 6;
            uint4 w = *(const uint4*)(bm + (size_t)(rowb + brow) * BMW + chunk * NSTEP + bk * 4);
            *(uint4*)&bmlds[brow][bk * 4] = w;   // 28%4==0 -> 16B aligned
        }
    }

    const float gm  = gmaxp[0];
    const float s2r = s2[prow];
    const float zub = s2r + gm;
    const float Mi  = fmaxf(zub, 0.2f * zub);   // lrelu(upper bound) >= every row logit

    // ---- hbT staging: wave wid stages feats wid*16..+16 via 1 gload16
    const int hrow  = wid * 16 + (lane >> 2);
    const int hcol8 = ((lane & 3) ^ ((lane >> 3) & 3)) * 8;
    const unsigned short* hgp0 = hbT + (size_t)hrow * NR + j0 + hcol8;
    const int hldso0 = wid * 16 * 64;
    const int h_base = r * 64 + ((g ^ ((r >> 1) & 3)) * 16);    // + f*1024

#define ISSUE(st) do { \
        const int sl_ = (st) % 3; \
        const size_t go_ = (size_t)(((st) % NSTEP) * 32); \
        gload16(hgp0 + go_, (char*)&hbtring[sl_][0] + hldso0); \
    } while (0)

    float lsum = 0.f;
    f32x4 acc[8];
#pragma unroll
    for (int f = 0; f < 8; ++f) acc[f] = f32x4{0.f, 0.f, 0.f, 0.f};

    ISSUE(0);
    ISSUE(1);

    const unsigned* bmrow = &bmlds[wid * 16 + r][0];
    const unsigned gsh = g * 8;

    for (int j = 0; j < NSTEP; ++j) {
        // stage j landed when <=1 of this wave's vmem remain (stage j+1 only).
        asm volatile("s_waitcnt vmcnt(1) lgkmcnt(0)" ::: "memory");
        __builtin_amdgcn_s_barrier();
        __builtin_amdgcn_sched_barrier(0);
        ISSUE(j + 2);   // slot (j+2)%3 == (j-1)%3, consumed before the barrier

        const unsigned mw = bmrow[j] >> gsh;    // bits 0..7 = this lane's 8 cols
        const float4 Sa = *(const float4*)&s1lds[j * 32 + g * 8];
        const float4 Sb = *(const float4*)&s1lds[j * 32 + g * 8 + 4];

        bf16x8 pf;
#define PROC(bi, ss, idx) { \
            float t0 = (ss) + s2r; \
            float lr = fmaxf(t0, 0.2f * t0); \
            float q  = __expf(lr - Mi); \
            float p  = ((mw >> (bi)) & 1u) ? q : 0.f; \
            lsum += p; \
            pf[idx] = (__bf16)p; }
        PROC(0, Sa.x, 0) PROC(1, Sa.y, 1)
        PROC(2, Sa.z, 2) PROC(3, Sa.w, 3)
        PROC(4, Sb.x, 4) PROC(5, Sb.y, 5)
        PROC(6, Sb.z, 6) PROC(7, Sb.w, 7)
#undef PROC

        const int sl = j % 3;
        const char* hb = (const char*)&hbtring[sl][0] + h_base;
#pragma unroll
        for (int f = 0; f < 8; ++f) {
            bf16x8 bfr = *(const bf16x8*)(hb + f * 1024);
            acc[f] = __builtin_amdgcn_mfma_f32_16x16x32_bf16(pf, bfr, acc[f], 0, 0, 0);
        }
    }
#undef ISSUE

    lsum += __shfl_xor(lsum, 16);
    lsum += __shfl_xor(lsum, 32);
    if (g == 0) lC[(size_t)chunk * NR + prow] = lsum;

    __half* nb = num + (size_t)chunk * NR * DF;
#pragma unroll
    for (int f = 0; f < 8; ++f)
#pragma unroll
        for (int q = 0; q < 4; ++q) {
            int row = rowb + wid * 16 + g * 4 + q;   // C/D layout: row=(lane>>4)*4+reg
            nb[(size_t)row * DF + f * 16 + r] = __float2half(acc[f][q]);
        }
}

// ---------- Kernel C: combine chunk partials (shared M_i -> plain sums) ------
__global__ __launch_bounds__(256) void k_comb(
    const __half* __restrict__ num, const float* __restrict__ lC,
    float* __restrict__ out)
{
    const int t   = threadIdx.x;
    const int row = blockIdx.x * 2 + (t >> 7);
    const int f   = t & 127;
    float L = 0.f, o = 0.f;
    for (int c = 0; c < CH; ++c) {
        L += lC[(size_t)c * NR + row];
        o += __half2float(num[(size_t)c * NR * DF + (size_t)row * DF + f]);
    }
    out[(size_t)row * DF + f] = o / L;
}

extern "C" void kernel_launch(void* const* d_in, const int* in_sizes, int n_in,
                              void* d_out, int out_size, void* d_ws, size_t ws_size,
                              hipStream_t stream)
{
    const float* x   = (const float*)d_in[0];
    const int*   adj = (const int*)d_in[1];
    const float* W   = (const float*)d_in[2];
    const float* a1  = (const float*)d_in[3];
    const float* a2  = (const float*)d_in[4];
    float* out = (float*)d_out;

    char* p = (char*)d_ws;
    unsigned short* hbT = (unsigned short*)p; p += (size_t)DF * NR * 2;
    unsigned*       bmw = (unsigned*)p;       p += (size_t)NR * BMW * 4;
    float*          s1  = (float*)p;          p += (size_t)NR * 4;
    float*          s2  = (float*)p;          p += (size_t)NR * 4;
    float*          gmx = (float*)p;          p += 256;
    __half*         numb = (__half*)p;        p += (size_t)CH * NR * DF * 2;
    float*          lC   = (float*)p;

    k_compress<<<2048, 256, 0, stream>>>(adj, bmw);
    k_gemm_h<<<NR / 64, 256, 0, stream>>>(x, W, a1, a2, hbT, s1, s2);
    k_gmax<<<1, 1024, 0, stream>>>(s1, gmx);
    k_flash<<<dim3(NR / ROWS, CH), 512, 0, stream>>>(bmw, hbT, s1, s2, gmx, numb, lC);
    k_comb<<<NR / 2, 256, 0, stream>>>(numb, lC, out);
}